// Round 2
// 757.333 us; speedup vs baseline: 1.1524x; 1.1524x over previous
//
#include <hip/hip_runtime.h>
#include <math.h>

// Workspace layout (floats):
//   G    [4][64][64] @ 0      (16384)  -- raw Gram sums, atomically accumulated
//   Sc   [4][64]     @ 16384  (256)    -- channel sums of cF
//   Ss   [4][64]     @ 16640  (256)    -- channel sums of sF
//   T    [4][64][64] @ 16896  (16384)  -- fused transform alpha*CM*F + (1-a)I
//   bias [4][64]     @ 33280  (256)
#define WS_G 0
#define WS_SC 16384
#define WS_SS 16640
#define WS_T 16896
#define WS_BIAS 33280
#define WS_ZERO_COUNT 16896

typedef __attribute__((ext_vector_type(8))) short bf16x8;
typedef __attribute__((ext_vector_type(16))) float f32x16;

__device__ __forceinline__ float waveRed(float v) {
#pragma unroll
    for (int o = 32; o > 0; o >>= 1) v += __shfl_down(v, o, 64);
    return v;
}

__global__ void zero_kernel(float* __restrict__ ws, int n) {
    int i = blockIdx.x * 256 + threadIdx.x;
    if (i < n) ws[i] = 0.f;
}

// Per-channel sums of x ([256 channels][N]); 8 blocks per channel.
__global__ __launch_bounds__(256) void sum_kernel(const float* __restrict__ x,
                                                  float* __restrict__ sums, int N) {
    const int ch = blockIdx.x >> 3;
    const int part = blockIdx.x & 7;
    const int seg = N >> 3;
    const float4* p = reinterpret_cast<const float4*>(x + (size_t)ch * N + (size_t)part * seg);
    const int nf4 = seg >> 2;
    float acc = 0.f;
    for (int i = threadIdx.x; i < nf4; i += 256) {
        float4 v = p[i];
        acc += (v.x + v.y) + (v.z + v.w);
    }
    acc = waveRed(acc);
    __shared__ float red[4];
    if ((threadIdx.x & 63) == 0) red[threadIdx.x >> 6] = acc;
    __syncthreads();
    if (threadIdx.x == 0) atomicAdd(&sums[ch], (red[0] + red[1]) + (red[2] + red[3]));
}

// ---------------------------------------------------------------------------
// MFMA Gram kernel: G[b] += cf_chunk * cf_chunk^T via split-bf16 (hi/lo) with
// 3 bf16 MFMA products (hi*hi + hi*lo + lo*hi); lo*lo dropped (~2^-17 rel).
// LDS layout per plane: 16 slabs (8 k-cols each) x [64 rows][8 bf16 = 16B],
// slab stride 1040 B (multiple of 16) -> contiguous 16B/lane ds_read_b128.
// Each wave owns one 32x32 output tile (I,J in {0,32}).
// ---------------------------------------------------------------------------
#define GR_SLAB 1040          // bytes per slab: 64 rows * 16B + 16B pad
#define GR_PLANE 16640        // 16 slabs * 1040
__global__ __launch_bounds__(256) void gram_kernel(const float* __restrict__ cF,
                                                   float* __restrict__ G,
                                                   float* __restrict__ Sc, int N) {
    __shared__ __align__(16) char smem[2 * GR_PLANE];  // hi plane @0, lo plane @GR_PLANE
    const int b = blockIdx.x >> 7;
    const int part = blockIdx.x & 127;
    const float* base = cF + (size_t)b * 64 * N + (size_t)part * (N >> 7);
    const int t = threadIdx.x;
    const int wid = t >> 6;
    const int lane = t & 63;
    const int I = (wid >> 1) << 5;
    const int Jt = (wid & 1) << 5;
    const bool diag = (I == Jt);
    const int rA = I + (lane & 31);
    const int rB = Jt + (lane & 31);
    const int sl = lane >> 5;

    f32x16 acc = {};
    float rs[8];
#pragma unroll
    for (int i = 0; i < 8; ++i) rs[i] = 0.f;

    // prefetch chunk 0
    float4 v[8];
#pragma unroll
    for (int i = 0; i < 8; ++i) {
        int f = t + 256 * i;
        v[i] = *reinterpret_cast<const float4*>(base + (size_t)(f >> 5) * N + (f & 31) * 4);
    }

    for (int c = 0; c < 16; ++c) {
        // convert staged regs -> packed hi/lo bf16 words
        uint2 hw[8], lw[8];
#pragma unroll
        for (int i = 0; i < 8; ++i) {
            float4 x = v[i];
            rs[i] += (x.x + x.y) + (x.z + x.w);
            unsigned bx = __float_as_uint(x.x), by = __float_as_uint(x.y);
            unsigned bz = __float_as_uint(x.z), bw = __float_as_uint(x.w);
            float lx = x.x - __uint_as_float(bx & 0xffff0000u);
            float ly = x.y - __uint_as_float(by & 0xffff0000u);
            float lz = x.z - __uint_as_float(bz & 0xffff0000u);
            float lwv = x.w - __uint_as_float(bw & 0xffff0000u);
            hw[i] = make_uint2((bx >> 16) | (by & 0xffff0000u),
                               (bz >> 16) | (bw & 0xffff0000u));
            lw[i] = make_uint2((__float_as_uint(lx) >> 16) | (__float_as_uint(ly) & 0xffff0000u),
                               (__float_as_uint(lz) >> 16) | (__float_as_uint(lwv) & 0xffff0000u));
        }
        __syncthreads();  // previous chunk's MFMA reads done
#pragma unroll
        for (int i = 0; i < 8; ++i) {
            int f = t + 256 * i;
            int row = f >> 5, col4 = f & 31;
            char* dst = smem + (col4 >> 1) * GR_SLAB + row * 16 + ((col4 & 1) << 3);
            *reinterpret_cast<uint2*>(dst) = hw[i];
            *reinterpret_cast<uint2*>(dst + GR_PLANE) = lw[i];
        }
        // prefetch next chunk while this one is consumed
        if (c < 15) {
            const float* gn = base + (c + 1) * 128;
#pragma unroll
            for (int i = 0; i < 8; ++i) {
                int f = t + 256 * i;
                v[i] = *reinterpret_cast<const float4*>(gn + (size_t)(f >> 5) * N + (f & 31) * 4);
            }
        }
        __syncthreads();  // LDS planes ready
#pragma unroll
        for (int kc = 0; kc < 8; ++kc) {
            const char* sb = smem + (2 * kc + sl) * GR_SLAB;
            bf16x8 ahi = *reinterpret_cast<const bf16x8*>(sb + rA * 16);
            bf16x8 alo = *reinterpret_cast<const bf16x8*>(sb + GR_PLANE + rA * 16);
            bf16x8 bhi, blo;
            if (diag) {
                bhi = ahi; blo = alo;
            } else {
                bhi = *reinterpret_cast<const bf16x8*>(sb + rB * 16);
                blo = *reinterpret_cast<const bf16x8*>(sb + GR_PLANE + rB * 16);
            }
            acc = __builtin_amdgcn_mfma_f32_32x32x16_bf16(ahi, bhi, acc, 0, 0, 0);
            acc = __builtin_amdgcn_mfma_f32_32x32x16_bf16(ahi, blo, acc, 0, 0, 0);
            acc = __builtin_amdgcn_mfma_f32_32x32x16_bf16(alo, bhi, acc, 0, 0, 0);
        }
        __syncthreads();  // reads done before next chunk's writes
    }

    // write Gram tile: C/D layout col=lane&31, row=(r&3)+8*(r>>2)+4*(lane>>5)
    float* Gb = G + b * 4096;
#pragma unroll
    for (int r = 0; r < 16; ++r) {
        int m = (r & 3) + 8 * (r >> 2) + 4 * (lane >> 5);
        int n = lane & 31;
        atomicAdd(&Gb[(I + m) * 64 + (Jt + n)], acc[r]);
    }
    // row sums: thread t's i-th stage row is (t>>5)+8i, constant across chunks.
    const int baseRow = t >> 5;
#pragma unroll
    for (int i = 0; i < 8; ++i) {
        float s = rs[i];
#pragma unroll
        for (int o = 16; o > 0; o >>= 1) s += __shfl_xor(s, o);
        if ((lane & 31) == 0) atomicAdd(&Sc[b * 64 + baseRow + 8 * i], s);
    }
}

// ---------- solver: cov -> Newton-Schulz inverse sqrt -> fused transform ----------
#define SSTR 68  // multiple of 4 => float4-aligned rows; bank = (4r + c) % 32

__device__ __forceinline__ void matmul44(float* __restrict__ D, const float* __restrict__ A,
                                         const float* __restrict__ Bm, int i0, int j0) {
    // D[i0..+3][j0..+3] = sum_k A[i][k] * B[k][j]; D must not alias A or Bm.
    float acc[4][4];
#pragma unroll
    for (int i = 0; i < 4; ++i)
#pragma unroll
        for (int j = 0; j < 4; ++j) acc[i][j] = 0.f;
    for (int k = 0; k < 64; ++k) {
        float4 bv = *reinterpret_cast<const float4*>(&Bm[k * SSTR + j0]);
        float a0 = A[(i0 + 0) * SSTR + k];
        float a1 = A[(i0 + 1) * SSTR + k];
        float a2 = A[(i0 + 2) * SSTR + k];
        float a3 = A[(i0 + 3) * SSTR + k];
        acc[0][0] += a0 * bv.x; acc[0][1] += a0 * bv.y; acc[0][2] += a0 * bv.z; acc[0][3] += a0 * bv.w;
        acc[1][0] += a1 * bv.x; acc[1][1] += a1 * bv.y; acc[1][2] += a1 * bv.z; acc[1][3] += a1 * bv.w;
        acc[2][0] += a2 * bv.x; acc[2][1] += a2 * bv.y; acc[2][2] += a2 * bv.z; acc[2][3] += a2 * bv.w;
        acc[3][0] += a3 * bv.x; acc[3][1] += a3 * bv.y; acc[3][2] += a3 * bv.z; acc[3][3] += a3 * bv.w;
    }
#pragma unroll
    for (int i = 0; i < 4; ++i)
#pragma unroll
        for (int j = 0; j < 4; ++j) D[(i0 + i) * SSTR + j0 + j] = acc[i][j];
}

__global__ __launch_bounds__(256) void solve_kernel(const float* __restrict__ G,
                                                    const float* __restrict__ Sc,
                                                    const float* __restrict__ Ss,
                                                    const float* __restrict__ alphap,
                                                    const float* __restrict__ s_e,
                                                    const float* __restrict__ s_v,
                                                    float* __restrict__ Tg,
                                                    float* __restrict__ biasg, int N) {
    __shared__ __align__(16) float Abuf[64 * SSTR];
    __shared__ __align__(16) float Ybuf[64 * SSTR];
    __shared__ __align__(16) float Tbuf[64 * SSTR];
    __shared__ __align__(16) float Wb[64 * 20];
    __shared__ float sdv[64], mcv[64], msv[64];
    __shared__ float redv;
    const int b = blockIdx.x, t = threadIdx.x;
    const int i0 = (t >> 4) << 2, j0 = (t & 15) << 2;
    const float invN = 1.f / (float)N;
    const float invNm1 = 1.f / (float)(N - 1);
    if (t < 64) {
        mcv[t] = Sc[b * 64 + t] * invN;
        msv[t] = Ss[b * 64 + t] * invN;
        sdv[t] = sqrtf(s_e[b * 64 + t]);
    }
    __syncthreads();
    // cov = (G - N*mu*mu^T)/(N-1) + I
#pragma unroll
    for (int i = 0; i < 4; ++i) {
        float mi = mcv[i0 + i];
#pragma unroll
        for (int j = 0; j < 4; ++j) {
            float g = G[b * 4096 + (i0 + i) * 64 + j0 + j];
            float cov = (g - mi * mcv[j0 + j] * (float)N) * invNm1 + (((i0 + i) == (j0 + j)) ? 1.f : 0.f);
            Abuf[(i0 + i) * SSTR + j0 + j] = cov;
        }
    }
    __syncthreads();
    if (t < 64) {
        float d = waveRed(Abuf[t * SSTR + t]);
        if (t == 0) redv = d * (1.f / 64.f);
    }
    __syncthreads();
    const float s = redv;
    const float inv_s = 1.f / s;
#pragma unroll
    for (int i = 0; i < 4; ++i)
#pragma unroll
        for (int j = 0; j < 4; ++j) {
            Abuf[(i0 + i) * SSTR + j0 + j] *= inv_s;  // A = cov/s, eigs ~ 1 +- 0.02
            Ybuf[(i0 + i) * SSTR + j0 + j] = ((i0 + i) == (j0 + j)) ? 1.f : 0.f;
        }
    __syncthreads();
    // Newton-Schulz: Y <- 0.5 * Y * (3I - A*Y*Y); 3 iters => fp32-exact (||I-A||~0.016)
    const int kr = t >> 2;         // 0..63
    const int cw = (t & 3) << 2;   // 0,4,8,12
    for (int it = 0; it < 3; ++it) {
        matmul44(Tbuf, Ybuf, Ybuf, i0, j0);  // Tbuf = Y*Y
        __syncthreads();
        for (int lb = 0; lb < 4; ++lb) {
            const int cb = lb << 4;
            float w0 = 0.f, w1 = 0.f, w2 = 0.f, w3 = 0.f;
            for (int j = 0; j < 64; ++j) {
                float a = Abuf[kr * SSTR + j];
                float4 tv = *reinterpret_cast<const float4*>(&Tbuf[j * SSTR + cb + cw]);
                w0 += a * tv.x; w1 += a * tv.y; w2 += a * tv.z; w3 += a * tv.w;
            }
            Wb[kr * 20 + cw + 0] = ((kr == cb + cw + 0) ? 1.5f : 0.f) - 0.5f * w0;
            Wb[kr * 20 + cw + 1] = ((kr == cb + cw + 1) ? 1.5f : 0.f) - 0.5f * w1;
            Wb[kr * 20 + cw + 2] = ((kr == cb + cw + 2) ? 1.5f : 0.f) - 0.5f * w2;
            Wb[kr * 20 + cw + 3] = ((kr == cb + cw + 3) ? 1.5f : 0.f) - 0.5f * w3;
            __syncthreads();
            float y0 = 0.f, y1 = 0.f, y2 = 0.f, y3 = 0.f;
            for (int k = 0; k < 64; ++k) {
                float a = Ybuf[kr * SSTR + k];
                float4 wv = *reinterpret_cast<const float4*>(&Wb[k * 20 + cw]);
                y0 += a * wv.x; y1 += a * wv.y; y2 += a * wv.z; y3 += a * wv.w;
            }
            Tbuf[kr * SSTR + cb + cw + 0] = y0;
            Tbuf[kr * SSTR + cb + cw + 1] = y1;
            Tbuf[kr * SSTR + cb + cw + 2] = y2;
            Tbuf[kr * SSTR + cb + cw + 3] = y3;
            __syncthreads();
        }
#pragma unroll
        for (int i = 0; i < 4; ++i)
#pragma unroll
            for (int j = 0; j < 4; ++j)
                Ybuf[(i0 + i) * SSTR + j0 + j] = Tbuf[(i0 + i) * SSTR + j0 + j];
        __syncthreads();
    }
    // Ybuf ~ (cov/s)^{-1/2}; F = Ybuf / sqrt(s)
    // colorM = s_v * diag(sqrt(s_e)) * s_v^T  (into Tbuf, s_v staged in Abuf)
    for (int i = 0; i < 16; ++i) {
        int idx = t + 256 * i;
        Abuf[(idx >> 6) * SSTR + (idx & 63)] = s_v[b * 4096 + idx];
    }
    __syncthreads();
    {
        float acc[4][4];
#pragma unroll
        for (int i = 0; i < 4; ++i)
#pragma unroll
            for (int j = 0; j < 4; ++j) acc[i][j] = 0.f;
        for (int k = 0; k < 64; ++k) {
            float sd = sdv[k];
            float a0 = Abuf[(i0 + 0) * SSTR + k] * sd;
            float a1 = Abuf[(i0 + 1) * SSTR + k] * sd;
            float a2 = Abuf[(i0 + 2) * SSTR + k] * sd;
            float a3 = Abuf[(i0 + 3) * SSTR + k] * sd;
            float c0v = Abuf[(j0 + 0) * SSTR + k];
            float c1v = Abuf[(j0 + 1) * SSTR + k];
            float c2v = Abuf[(j0 + 2) * SSTR + k];
            float c3v = Abuf[(j0 + 3) * SSTR + k];
            acc[0][0] += a0 * c0v; acc[0][1] += a0 * c1v; acc[0][2] += a0 * c2v; acc[0][3] += a0 * c3v;
            acc[1][0] += a1 * c0v; acc[1][1] += a1 * c1v; acc[1][2] += a1 * c2v; acc[1][3] += a1 * c3v;
            acc[2][0] += a2 * c0v; acc[2][1] += a2 * c1v; acc[2][2] += a2 * c2v; acc[2][3] += a2 * c3v;
            acc[3][0] += a3 * c0v; acc[3][1] += a3 * c1v; acc[3][2] += a3 * c2v; acc[3][3] += a3 * c3v;
        }
        __syncthreads();
#pragma unroll
        for (int i = 0; i < 4; ++i)
#pragma unroll
            for (int j = 0; j < 4; ++j) Tbuf[(i0 + i) * SSTR + j0 + j] = acc[i][j];
    }
    __syncthreads();
    matmul44(Abuf, Tbuf, Ybuf, i0, j0);  // Abuf = colorM * Y  (scale below)
    __syncthreads();
    const float alpha_v = alphap[0];
    const float fac = alpha_v / sqrtf(s);  // alpha / sqrt(s): M2 = fac * Abuf
#pragma unroll
    for (int i = 0; i < 4; ++i)
#pragma unroll
        for (int j = 0; j < 4; ++j) {
            float m = Abuf[(i0 + i) * SSTR + j0 + j] * fac;
            if ((i0 + i) == (j0 + j)) m += 1.f - alpha_v;
            Tg[b * 4096 + (i0 + i) * 64 + j0 + j] = m;
        }
    if (t < 64) {
        float acc = 0.f;
        for (int d = 0; d < 64; ++d) acc += Abuf[t * SSTR + d] * mcv[d];
        biasg[b * 64 + t] = alpha_v * msv[t] - fac * acc;
    }
}

// Apply: out[c][x] = sum_k T[c][k]*cf[k][x] + bias[c]
// tile stride 132 (multiple of 4): float4 reads at fixed row k across lanes are conflict-free.
#define ASTR 132
__global__ __launch_bounds__(256) void apply_kernel(const float* __restrict__ cF,
                                                    const float* __restrict__ T,
                                                    const float* __restrict__ bias,
                                                    float* __restrict__ out, int N) {
    __shared__ __align__(16) float tile[64 * ASTR];
    __shared__ float Tl[64 * 65];
    __shared__ float bl[64];
    const int b = blockIdx.x >> 9;
    const int part = blockIdx.x & 511;
    const int chunk = N >> 9;  // 512
    const float* src = cF + (size_t)b * 64 * N + (size_t)part * chunk;
    float* dst = out + (size_t)b * 64 * N + (size_t)part * chunk;
    const int t = threadIdx.x;
    for (int i = 0; i < 16; ++i) {
        int idx = t + 256 * i;
        Tl[(idx >> 6) * 65 + (idx & 63)] = T[b * 4096 + idx];
    }
    if (t < 64) bl[t] = bias[b * 64 + t];
    const int x0 = (t & 7) * 4;
    const int cA = (t >> 3) * 2;
    for (int sub = 0; sub < 4; ++sub) {
        __syncthreads();  // Tl ready / previous compute done
        const float* gsrc = src + sub * 128;
#pragma unroll
        for (int i = 0; i < 8; ++i) {
            int f = t + 256 * i;
            int row = f >> 5, col4 = f & 31;
            *reinterpret_cast<float4*>(&tile[row * ASTR + col4 * 4]) =
                *reinterpret_cast<const float4*>(gsrc + (size_t)row * N + col4 * 4);
        }
        __syncthreads();
        float b0 = bl[cA], b1 = bl[cA + 1];
        float4 acc0[4], acc1[4];
#pragma unroll
        for (int g = 0; g < 4; ++g) {
            acc0[g] = make_float4(b0, b0, b0, b0);
            acc1[g] = make_float4(b1, b1, b1, b1);
        }
        const float* t0 = &Tl[cA * 65];
        const float* t1 = &Tl[(cA + 1) * 65];
#pragma unroll 2
        for (int k = 0; k < 64; ++k) {
            float a0 = t0[k], a1 = t1[k];
            const float* trow = &tile[k * ASTR + x0];
#pragma unroll
            for (int g = 0; g < 4; ++g) {
                float4 v = *reinterpret_cast<const float4*>(trow + 32 * g);
                acc0[g].x += a0 * v.x; acc0[g].y += a0 * v.y; acc0[g].z += a0 * v.z; acc0[g].w += a0 * v.w;
                acc1[g].x += a1 * v.x; acc1[g].y += a1 * v.y; acc1[g].z += a1 * v.z; acc1[g].w += a1 * v.w;
            }
        }
        float* d0 = dst + (size_t)cA * N + sub * 128 + x0;
        float* d1 = dst + (size_t)(cA + 1) * N + sub * 128 + x0;
#pragma unroll
        for (int g = 0; g < 4; ++g) {
            *reinterpret_cast<float4*>(d0 + 32 * g) = acc0[g];
            *reinterpret_cast<float4*>(d1 + 32 * g) = acc1[g];
        }
    }
}

extern "C" void kernel_launch(void* const* d_in, const int* in_sizes, int n_in,
                              void* d_out, int out_size, void* d_ws, size_t ws_size,
                              hipStream_t stream) {
    const float* cF = (const float*)d_in[0];
    const float* sF = (const float*)d_in[1];
    const float* alpha = (const float*)d_in[2];
    const float* s_e = (const float*)d_in[3];
    const float* s_v = (const float*)d_in[4];
    float* out = (float*)d_out;
    float* ws = (float*)d_ws;
    const int B = 4, C = 64;
    const int N = in_sizes[0] / (B * C);  // 262144
    float* G = ws + WS_G;
    float* Sc = ws + WS_SC;
    float* Ss = ws + WS_SS;
    float* T = ws + WS_T;
    float* bias = ws + WS_BIAS;
    hipLaunchKernelGGL(zero_kernel, dim3(66), dim3(256), 0, stream, ws, WS_ZERO_COUNT);
    hipLaunchKernelGGL(sum_kernel, dim3(B * C * 8), dim3(256), 0, stream, sF, Ss, N);
    hipLaunchKernelGGL(gram_kernel, dim3(B * 128), dim3(256), 0, stream, cF, G, Sc, N);
    hipLaunchKernelGGL(solve_kernel, dim3(B), dim3(256), 0, stream, G, Sc, Ss, alpha, s_e, s_v, T, bias, N);
    hipLaunchKernelGGL(apply_kernel, dim3(B * 512), dim3(256), 0, stream, cF, T, bias, out, N);
}

// Round 3
// 737.162 us; speedup vs baseline: 1.1840x; 1.0274x over previous
//
#include <hip/hip_runtime.h>
#include <math.h>

// Workspace layout (floats):
//   G    [4][64][64] @ 0      (16384)  -- raw Gram sums, atomically accumulated
//   Sc   [4][64]     @ 16384  (256)    -- channel sums of cF
//   Ss   [4][64]     @ 16640  (256)    -- channel sums of sF
//   T    [4][64][64] @ 16896  (16384)  -- fused transform alpha*CM*F + (1-a)I
//   bias [4][64]     @ 33280  (256)
#define WS_G 0
#define WS_SC 16384
#define WS_SS 16640
#define WS_T 16896
#define WS_BIAS 33280
#define WS_ZERO_COUNT 16896

typedef __attribute__((ext_vector_type(8))) short bf16x8;
typedef __attribute__((ext_vector_type(16))) float f32x16;

__device__ __forceinline__ float waveRed(float v) {
#pragma unroll
    for (int o = 32; o > 0; o >>= 1) v += __shfl_down(v, o, 64);
    return v;
}

__global__ void zero_kernel(float* __restrict__ ws, int n) {
    int i = blockIdx.x * 256 + threadIdx.x;
    if (i < n) ws[i] = 0.f;
}

// ---------------------------------------------------------------------------
// pre_kernel: fused {channel sums of sF} + {MFMA Gram of cF + channel sums}.
// blocks [0..2047]  : sum path   (ch = bid>>3, 8 parts per channel)
// blocks [2048..2559]: gram path (b = bid2>>7, 128 parts per batch)
// Fusing lets both HBM streams co-schedule instead of serializing.
// ---------------------------------------------------------------------------
#define GR_SLAB 1040          // bytes per slab: 64 rows * 16B + 16B pad
#define GR_PLANE 16640        // 16 slabs * 1040
__global__ __launch_bounds__(256) void pre_kernel(const float* __restrict__ cF,
                                                  const float* __restrict__ sF,
                                                  float* __restrict__ G,
                                                  float* __restrict__ Sc,
                                                  float* __restrict__ Ss, int N) {
    __shared__ __align__(16) char smem[2 * GR_PLANE];  // hi plane @0, lo plane @GR_PLANE
    const int t = threadIdx.x;
    if (blockIdx.x < 2048) {
        // ---- sum path: per-channel sums of sF ----
        const int ch = blockIdx.x >> 3;
        const int part = blockIdx.x & 7;
        const int seg = N >> 3;
        const float4* p = reinterpret_cast<const float4*>(sF + (size_t)ch * N + (size_t)part * seg);
        const int nf4 = seg >> 2;
        float acc = 0.f;
        for (int i = t; i < nf4; i += 256) {
            float4 v = p[i];
            acc += (v.x + v.y) + (v.z + v.w);
        }
        acc = waveRed(acc);
        float* red = reinterpret_cast<float*>(smem);
        if ((t & 63) == 0) red[t >> 6] = acc;
        __syncthreads();
        if (t == 0) atomicAdd(&Ss[ch], (red[0] + red[1]) + (red[2] + red[3]));
        return;
    }
    // ---- gram path: G[b] += cf_chunk * cf_chunk^T via split-bf16 MFMA ----
    const int bid2 = blockIdx.x - 2048;
    const int b = bid2 >> 7;
    const int part = bid2 & 127;
    const float* base = cF + (size_t)b * 64 * N + (size_t)part * (N >> 7);
    const int wid = t >> 6;
    const int lane = t & 63;
    const int I = (wid >> 1) << 5;
    const int Jt = (wid & 1) << 5;
    const bool diag = (I == Jt);
    const int rA = I + (lane & 31);
    const int rB = Jt + (lane & 31);
    const int sl = lane >> 5;

    f32x16 acc = {};
    float rs[8];
#pragma unroll
    for (int i = 0; i < 8; ++i) rs[i] = 0.f;

    // prefetch chunk 0
    float4 v[8];
#pragma unroll
    for (int i = 0; i < 8; ++i) {
        int f = t + 256 * i;
        v[i] = *reinterpret_cast<const float4*>(base + (size_t)(f >> 5) * N + (f & 31) * 4);
    }

    for (int c = 0; c < 16; ++c) {
        uint2 hw[8], lw[8];
#pragma unroll
        for (int i = 0; i < 8; ++i) {
            float4 x = v[i];
            rs[i] += (x.x + x.y) + (x.z + x.w);
            unsigned bx = __float_as_uint(x.x), by = __float_as_uint(x.y);
            unsigned bz = __float_as_uint(x.z), bw = __float_as_uint(x.w);
            float lx = x.x - __uint_as_float(bx & 0xffff0000u);
            float ly = x.y - __uint_as_float(by & 0xffff0000u);
            float lz = x.z - __uint_as_float(bz & 0xffff0000u);
            float lwv = x.w - __uint_as_float(bw & 0xffff0000u);
            hw[i] = make_uint2((bx >> 16) | (by & 0xffff0000u),
                               (bz >> 16) | (bw & 0xffff0000u));
            lw[i] = make_uint2((__float_as_uint(lx) >> 16) | (__float_as_uint(ly) & 0xffff0000u),
                               (__float_as_uint(lz) >> 16) | (__float_as_uint(lwv) & 0xffff0000u));
        }
        __syncthreads();  // previous chunk's MFMA reads done
#pragma unroll
        for (int i = 0; i < 8; ++i) {
            int f = t + 256 * i;
            int row = f >> 5, col4 = f & 31;
            char* dst = smem + (col4 >> 1) * GR_SLAB + row * 16 + ((col4 & 1) << 3);
            *reinterpret_cast<uint2*>(dst) = hw[i];
            *reinterpret_cast<uint2*>(dst + GR_PLANE) = lw[i];
        }
        if (c < 15) {
            const float* gn = base + (c + 1) * 128;
#pragma unroll
            for (int i = 0; i < 8; ++i) {
                int f = t + 256 * i;
                v[i] = *reinterpret_cast<const float4*>(gn + (size_t)(f >> 5) * N + (f & 31) * 4);
            }
        }
        __syncthreads();  // LDS planes ready
#pragma unroll
        for (int kc = 0; kc < 8; ++kc) {
            const char* sb = smem + (2 * kc + sl) * GR_SLAB;
            bf16x8 ahi = *reinterpret_cast<const bf16x8*>(sb + rA * 16);
            bf16x8 alo = *reinterpret_cast<const bf16x8*>(sb + GR_PLANE + rA * 16);
            bf16x8 bhi, blo;
            if (diag) {
                bhi = ahi; blo = alo;
            } else {
                bhi = *reinterpret_cast<const bf16x8*>(sb + rB * 16);
                blo = *reinterpret_cast<const bf16x8*>(sb + GR_PLANE + rB * 16);
            }
            acc = __builtin_amdgcn_mfma_f32_32x32x16_bf16(ahi, bhi, acc, 0, 0, 0);
            acc = __builtin_amdgcn_mfma_f32_32x32x16_bf16(ahi, blo, acc, 0, 0, 0);
            acc = __builtin_amdgcn_mfma_f32_32x32x16_bf16(alo, bhi, acc, 0, 0, 0);
        }
        __syncthreads();  // reads done before next chunk's writes
    }

    float* Gb = G + b * 4096;
#pragma unroll
    for (int r = 0; r < 16; ++r) {
        int m = (r & 3) + 8 * (r >> 2) + 4 * (lane >> 5);
        int n = lane & 31;
        atomicAdd(&Gb[(I + m) * 64 + (Jt + n)], acc[r]);
    }
    const int baseRow = t >> 5;
#pragma unroll
    for (int i = 0; i < 8; ++i) {
        float s = rs[i];
#pragma unroll
        for (int o = 16; o > 0; o >>= 1) s += __shfl_xor(s, o);
        if ((lane & 31) == 0) atomicAdd(&Sc[b * 64 + baseRow + 8 * i], s);
    }
}

// ---------- solver: cov -> Newton-Schulz inverse sqrt -> fused transform ----------
#define SSTR 68  // multiple of 4 => float4-aligned rows; bank = (4r + c) % 32

__device__ __forceinline__ void matmul44(float* __restrict__ D, const float* __restrict__ A,
                                         const float* __restrict__ Bm, int i0, int j0) {
    float acc[4][4];
#pragma unroll
    for (int i = 0; i < 4; ++i)
#pragma unroll
        for (int j = 0; j < 4; ++j) acc[i][j] = 0.f;
    for (int k = 0; k < 64; ++k) {
        float4 bv = *reinterpret_cast<const float4*>(&Bm[k * SSTR + j0]);
        float a0 = A[(i0 + 0) * SSTR + k];
        float a1 = A[(i0 + 1) * SSTR + k];
        float a2 = A[(i0 + 2) * SSTR + k];
        float a3 = A[(i0 + 3) * SSTR + k];
        acc[0][0] += a0 * bv.x; acc[0][1] += a0 * bv.y; acc[0][2] += a0 * bv.z; acc[0][3] += a0 * bv.w;
        acc[1][0] += a1 * bv.x; acc[1][1] += a1 * bv.y; acc[1][2] += a1 * bv.z; acc[1][3] += a1 * bv.w;
        acc[2][0] += a2 * bv.x; acc[2][1] += a2 * bv.y; acc[2][2] += a2 * bv.z; acc[2][3] += a2 * bv.w;
        acc[3][0] += a3 * bv.x; acc[3][1] += a3 * bv.y; acc[3][2] += a3 * bv.z; acc[3][3] += a3 * bv.w;
    }
#pragma unroll
    for (int i = 0; i < 4; ++i)
#pragma unroll
        for (int j = 0; j < 4; ++j) D[(i0 + i) * SSTR + j0 + j] = acc[i][j];
}

__global__ __launch_bounds__(256) void solve_kernel(const float* __restrict__ G,
                                                    const float* __restrict__ Sc,
                                                    const float* __restrict__ Ss,
                                                    const float* __restrict__ alphap,
                                                    const float* __restrict__ s_e,
                                                    const float* __restrict__ s_v,
                                                    float* __restrict__ Tg,
                                                    float* __restrict__ biasg, int N) {
    __shared__ __align__(16) float Abuf[64 * SSTR];
    __shared__ __align__(16) float Ybuf[64 * SSTR];
    __shared__ __align__(16) float Tbuf[64 * SSTR];
    __shared__ __align__(16) float Wb[64 * 20];
    __shared__ float sdv[64], mcv[64], msv[64];
    __shared__ float redv;
    const int b = blockIdx.x, t = threadIdx.x;
    const int i0 = (t >> 4) << 2, j0 = (t & 15) << 2;
    const float invN = 1.f / (float)N;
    const float invNm1 = 1.f / (float)(N - 1);
    if (t < 64) {
        mcv[t] = Sc[b * 64 + t] * invN;
        msv[t] = Ss[b * 64 + t] * invN;
        sdv[t] = sqrtf(s_e[b * 64 + t]);
    }
    __syncthreads();
#pragma unroll
    for (int i = 0; i < 4; ++i) {
        float mi = mcv[i0 + i];
#pragma unroll
        for (int j = 0; j < 4; ++j) {
            float g = G[b * 4096 + (i0 + i) * 64 + j0 + j];
            float cov = (g - mi * mcv[j0 + j] * (float)N) * invNm1 + (((i0 + i) == (j0 + j)) ? 1.f : 0.f);
            Abuf[(i0 + i) * SSTR + j0 + j] = cov;
        }
    }
    __syncthreads();
    if (t < 64) {
        float d = waveRed(Abuf[t * SSTR + t]);
        if (t == 0) redv = d * (1.f / 64.f);
    }
    __syncthreads();
    const float s = redv;
    const float inv_s = 1.f / s;
#pragma unroll
    for (int i = 0; i < 4; ++i)
#pragma unroll
        for (int j = 0; j < 4; ++j) {
            Abuf[(i0 + i) * SSTR + j0 + j] *= inv_s;
            Ybuf[(i0 + i) * SSTR + j0 + j] = ((i0 + i) == (j0 + j)) ? 1.f : 0.f;
        }
    __syncthreads();
    const int kr = t >> 2;
    const int cw = (t & 3) << 2;
    for (int it = 0; it < 3; ++it) {
        matmul44(Tbuf, Ybuf, Ybuf, i0, j0);
        __syncthreads();
        for (int lb = 0; lb < 4; ++lb) {
            const int cb = lb << 4;
            float w0 = 0.f, w1 = 0.f, w2 = 0.f, w3 = 0.f;
            for (int j = 0; j < 64; ++j) {
                float a = Abuf[kr * SSTR + j];
                float4 tv = *reinterpret_cast<const float4*>(&Tbuf[j * SSTR + cb + cw]);
                w0 += a * tv.x; w1 += a * tv.y; w2 += a * tv.z; w3 += a * tv.w;
            }
            Wb[kr * 20 + cw + 0] = ((kr == cb + cw + 0) ? 1.5f : 0.f) - 0.5f * w0;
            Wb[kr * 20 + cw + 1] = ((kr == cb + cw + 1) ? 1.5f : 0.f) - 0.5f * w1;
            Wb[kr * 20 + cw + 2] = ((kr == cb + cw + 2) ? 1.5f : 0.f) - 0.5f * w2;
            Wb[kr * 20 + cw + 3] = ((kr == cb + cw + 3) ? 1.5f : 0.f) - 0.5f * w3;
            __syncthreads();
            float y0 = 0.f, y1 = 0.f, y2 = 0.f, y3 = 0.f;
            for (int k = 0; k < 64; ++k) {
                float a = Ybuf[kr * SSTR + k];
                float4 wv = *reinterpret_cast<const float4*>(&Wb[k * 20 + cw]);
                y0 += a * wv.x; y1 += a * wv.y; y2 += a * wv.z; y3 += a * wv.w;
            }
            Tbuf[kr * SSTR + cb + cw + 0] = y0;
            Tbuf[kr * SSTR + cb + cw + 1] = y1;
            Tbuf[kr * SSTR + cb + cw + 2] = y2;
            Tbuf[kr * SSTR + cb + cw + 3] = y3;
            __syncthreads();
        }
#pragma unroll
        for (int i = 0; i < 4; ++i)
#pragma unroll
            for (int j = 0; j < 4; ++j)
                Ybuf[(i0 + i) * SSTR + j0 + j] = Tbuf[(i0 + i) * SSTR + j0 + j];
        __syncthreads();
    }
    for (int i = 0; i < 16; ++i) {
        int idx = t + 256 * i;
        Abuf[(idx >> 6) * SSTR + (idx & 63)] = s_v[b * 4096 + idx];
    }
    __syncthreads();
    {
        float acc[4][4];
#pragma unroll
        for (int i = 0; i < 4; ++i)
#pragma unroll
            for (int j = 0; j < 4; ++j) acc[i][j] = 0.f;
        for (int k = 0; k < 64; ++k) {
            float sd = sdv[k];
            float a0 = Abuf[(i0 + 0) * SSTR + k] * sd;
            float a1 = Abuf[(i0 + 1) * SSTR + k] * sd;
            float a2 = Abuf[(i0 + 2) * SSTR + k] * sd;
            float a3 = Abuf[(i0 + 3) * SSTR + k] * sd;
            float c0v = Abuf[(j0 + 0) * SSTR + k];
            float c1v = Abuf[(j0 + 1) * SSTR + k];
            float c2v = Abuf[(j0 + 2) * SSTR + k];
            float c3v = Abuf[(j0 + 3) * SSTR + k];
            acc[0][0] += a0 * c0v; acc[0][1] += a0 * c1v; acc[0][2] += a0 * c2v; acc[0][3] += a0 * c3v;
            acc[1][0] += a1 * c0v; acc[1][1] += a1 * c1v; acc[1][2] += a1 * c2v; acc[1][3] += a1 * c3v;
            acc[2][0] += a2 * c0v; acc[2][1] += a2 * c1v; acc[2][2] += a2 * c2v; acc[2][3] += a2 * c3v;
            acc[3][0] += a3 * c0v; acc[3][1] += a3 * c1v; acc[3][2] += a3 * c2v; acc[3][3] += a3 * c3v;
        }
        __syncthreads();
#pragma unroll
        for (int i = 0; i < 4; ++i)
#pragma unroll
            for (int j = 0; j < 4; ++j) Tbuf[(i0 + i) * SSTR + j0 + j] = acc[i][j];
    }
    __syncthreads();
    matmul44(Abuf, Tbuf, Ybuf, i0, j0);
    __syncthreads();
    const float alpha_v = alphap[0];
    const float fac = alpha_v / sqrtf(s);
#pragma unroll
    for (int i = 0; i < 4; ++i)
#pragma unroll
        for (int j = 0; j < 4; ++j) {
            float m = Abuf[(i0 + i) * SSTR + j0 + j] * fac;
            if ((i0 + i) == (j0 + j)) m += 1.f - alpha_v;
            Tg[b * 4096 + (i0 + i) * 64 + j0 + j] = m;
        }
    if (t < 64) {
        float acc = 0.f;
        for (int d = 0; d < 64; ++d) acc += Abuf[t * SSTR + d] * mcv[d];
        biasg[b * 64 + t] = alpha_v * msv[t] - fac * acc;
    }
}

// ---------------------------------------------------------------------------
// MFMA apply: out[c][x] = sum_k T[c][k]*cf[k][x] + bias[c], split-bf16.
// cf tile transposed into LDS as [x][k] (k contiguous): row = XSTR=72
// halfwords = 144 B (16B-aligned -> ds_read_b128 B-fragments).
// Each wave: 32 channels (I) x 64 pixels (xb0), T fragments in registers.
// Staging write conflicts + conversion VALU hide under the 64KB/block HBM
// stream (4 blocks/CU).
// ---------------------------------------------------------------------------
#define APX 128
#define XSTR 72
__global__ __launch_bounds__(256) void apply_kernel(const float* __restrict__ cF,
                                                    const float* __restrict__ Tg,
                                                    const float* __restrict__ biasg,
                                                    float* __restrict__ out, int N) {
    __shared__ __align__(16) unsigned short sx[2][APX][XSTR];  // hi, lo planes
    __shared__ float bl[64];
    const int b = blockIdx.x >> 11;
    const int part = blockIdx.x & 2047;
    const float* src = cF + (size_t)b * 64 * N + (size_t)part * APX;
    float* dst = out + (size_t)b * 64 * N + (size_t)part * APX;
    const int t = threadIdx.x;
    const int lane = t & 63;
    const int wid = t >> 6;
    if (t < 64) bl[t] = biasg[b * 64 + t];

    // --- T fragments (A operand), split bf16 hi/lo, from global (L2-hot) ---
    const int I = (wid & 1) << 5;        // channel block
    const int xb0 = (wid >> 1) << 6;     // pixel block (0 or 64)
    const int kb = (lane >> 5) << 3;     // k sub-slab within 16-k slab
    bf16x8 th[4], tl[4];
    {
        const float* Trow = Tg + b * 4096 + (size_t)(I + (lane & 31)) * 64;
#pragma unroll
        for (int ks = 0; ks < 4; ++ks) {
            float4 u0 = *reinterpret_cast<const float4*>(Trow + ks * 16 + kb);
            float4 u1 = *reinterpret_cast<const float4*>(Trow + ks * 16 + kb + 4);
            float v[8] = {u0.x, u0.y, u0.z, u0.w, u1.x, u1.y, u1.z, u1.w};
#pragma unroll
            for (int j = 0; j < 8; ++j) {
                unsigned u = __float_as_uint(v[j]);
                th[ks][j] = (short)(u >> 16);
                float r = v[j] - __uint_as_float(u & 0xffff0000u);
                tl[ks][j] = (short)(__float_as_uint(r) >> 16);
            }
        }
    }

    // --- stage cf[64][APX] -> transposed split-bf16 planes [x][k] ---
#pragma unroll
    for (int i = 0; i < 4; ++i) {
        int u = t + 256 * i;           // 0..1023
        int kp = u >> 5;               // k pair 0..31
        int x0 = (u & 31) << 2;        // pixel quad
        const float* ra = src + (size_t)(2 * kp) * N + x0;
        float4 va = *reinterpret_cast<const float4*>(ra);
        float4 vb = *reinterpret_cast<const float4*>(ra + N);
        float av[4] = {va.x, va.y, va.z, va.w};
        float bv[4] = {vb.x, vb.y, vb.z, vb.w};
#pragma unroll
        for (int j = 0; j < 4; ++j) {
            unsigned ua = __float_as_uint(av[j]);
            unsigned ub = __float_as_uint(bv[j]);
            float ral = av[j] - __uint_as_float(ua & 0xffff0000u);
            float rbl = bv[j] - __uint_as_float(ub & 0xffff0000u);
            unsigned hi = (ua >> 16) | (ub & 0xffff0000u);
            unsigned lo = (__float_as_uint(ral) >> 16) | (__float_as_uint(rbl) & 0xffff0000u);
            *reinterpret_cast<unsigned*>(&sx[0][x0 + j][2 * kp]) = hi;
            *reinterpret_cast<unsigned*>(&sx[1][x0 + j][2 * kp]) = lo;
        }
    }
    __syncthreads();

    // --- MFMA: acc = T_hi*x_hi + T_hi*x_lo + T_lo*x_hi ---
    f32x16 acc0 = {}, acc1 = {};
    const int xA = xb0 + (lane & 31);
#pragma unroll
    for (int ks = 0; ks < 4; ++ks) {
        const int ko = ks * 16 + kb;
        bf16x8 bh0 = *reinterpret_cast<const bf16x8*>(&sx[0][xA][ko]);
        bf16x8 bL0 = *reinterpret_cast<const bf16x8*>(&sx[1][xA][ko]);
        bf16x8 bh1 = *reinterpret_cast<const bf16x8*>(&sx[0][xA + 32][ko]);
        bf16x8 bL1 = *reinterpret_cast<const bf16x8*>(&sx[1][xA + 32][ko]);
        acc0 = __builtin_amdgcn_mfma_f32_32x32x16_bf16(th[ks], bh0, acc0, 0, 0, 0);
        acc0 = __builtin_amdgcn_mfma_f32_32x32x16_bf16(th[ks], bL0, acc0, 0, 0, 0);
        acc0 = __builtin_amdgcn_mfma_f32_32x32x16_bf16(tl[ks], bh0, acc0, 0, 0, 0);
        acc1 = __builtin_amdgcn_mfma_f32_32x32x16_bf16(th[ks], bh1, acc1, 0, 0, 0);
        acc1 = __builtin_amdgcn_mfma_f32_32x32x16_bf16(th[ks], bL1, acc1, 0, 0, 0);
        acc1 = __builtin_amdgcn_mfma_f32_32x32x16_bf16(tl[ks], bh1, acc1, 0, 0, 0);
    }

    // --- store + bias: C/D layout col=lane&31, row=(r&3)+8*(r>>2)+4*(lane>>5) ---
#pragma unroll
    for (int r = 0; r < 16; ++r) {
        int m = (r & 3) + 8 * (r >> 2) + 4 * (lane >> 5);
        float bb = bl[I + m];
        float* dr = dst + (size_t)(I + m) * N;
        dr[xA] = acc0[r] + bb;
        dr[xA + 32] = acc1[r] + bb;
    }
}

extern "C" void kernel_launch(void* const* d_in, const int* in_sizes, int n_in,
                              void* d_out, int out_size, void* d_ws, size_t ws_size,
                              hipStream_t stream) {
    const float* cF = (const float*)d_in[0];
    const float* sF = (const float*)d_in[1];
    const float* alpha = (const float*)d_in[2];
    const float* s_e = (const float*)d_in[3];
    const float* s_v = (const float*)d_in[4];
    float* out = (float*)d_out;
    float* ws = (float*)d_ws;
    const int B = 4, C = 64;
    const int N = in_sizes[0] / (B * C);  // 262144
    float* G = ws + WS_G;
    float* Sc = ws + WS_SC;
    float* Ss = ws + WS_SS;
    float* T = ws + WS_T;
    float* bias = ws + WS_BIAS;
    hipLaunchKernelGGL(zero_kernel, dim3(66), dim3(256), 0, stream, ws, WS_ZERO_COUNT);
    hipLaunchKernelGGL(pre_kernel, dim3(2048 + B * 128), dim3(256), 0, stream, cF, sF, G, Sc, Ss, N);
    hipLaunchKernelGGL(solve_kernel, dim3(B), dim3(256), 0, stream, G, Sc, Ss, alpha, s_e, s_v, T, bias, N);
    hipLaunchKernelGGL(apply_kernel, dim3(B * 2048), dim3(256), 0, stream, cF, T, bias, out, N);
}

// Round 4
// 727.201 us; speedup vs baseline: 1.2002x; 1.0137x over previous
//
#include <hip/hip_runtime.h>
#include <math.h>

// Workspace layout (floats):
//   G    [4][64][64] @ 0      (16384)  -- raw Gram sums, atomically accumulated
//   Sc   [4][64]     @ 16384  (256)    -- channel sums of cF
//   Ss   [4][64]     @ 16640  (256)    -- channel sums of sF
//   T    [4][64][64] @ 16896  (16384)  -- fused transform alpha*CM*F + (1-a)I
//   bias [4][64]     @ 33280  (256)
#define WS_G 0
#define WS_SC 16384
#define WS_SS 16640
#define WS_T 16896
#define WS_BIAS 33280
#define WS_ZERO_COUNT 16896

typedef __attribute__((ext_vector_type(8))) short bf16x8;
typedef __attribute__((ext_vector_type(16))) float f32x16;

__device__ __forceinline__ float waveRed(float v) {
#pragma unroll
    for (int o = 32; o > 0; o >>= 1) v += __shfl_down(v, o, 64);
    return v;
}

__global__ void zero_kernel(float* __restrict__ ws, int n) {
    int i = blockIdx.x * 256 + threadIdx.x;
    if (i < n) ws[i] = 0.f;
}

// Per-channel sums of x ([256 channels][N]); 8 blocks per channel.
// Tiny LDS (16 B) -> 8 blocks/CU; 4 loads in flight per thread.
__global__ __launch_bounds__(256) void sum_kernel(const float* __restrict__ x,
                                                  float* __restrict__ sums, int N) {
    const int ch = blockIdx.x >> 3;
    const int part = blockIdx.x & 7;
    const int seg = N >> 3;  // 32768
    const float4* p = reinterpret_cast<const float4*>(x + (size_t)ch * N + (size_t)part * seg);
    const int nf4 = seg >> 2;  // 8192
    float a0 = 0.f, a1 = 0.f, a2 = 0.f, a3 = 0.f;
    for (int i = threadIdx.x; i < nf4; i += 1024) {
        float4 v0 = p[i];
        float4 v1 = p[i + 256];
        float4 v2 = p[i + 512];
        float4 v3 = p[i + 768];
        a0 += (v0.x + v0.y) + (v0.z + v0.w);
        a1 += (v1.x + v1.y) + (v1.z + v1.w);
        a2 += (v2.x + v2.y) + (v2.z + v2.w);
        a3 += (v3.x + v3.y) + (v3.z + v3.w);
    }
    float acc = waveRed((a0 + a1) + (a2 + a3));
    __shared__ float red[4];
    if ((threadIdx.x & 63) == 0) red[threadIdx.x >> 6] = acc;
    __syncthreads();
    if (threadIdx.x == 0) atomicAdd(&sums[ch], (red[0] + red[1]) + (red[2] + red[3]));
}

// ---------------------------------------------------------------------------
// MFMA Gram kernel: G[b] += cf_chunk * cf_chunk^T via split-bf16 (hi/lo) with
// 3 bf16 MFMA products (hi*hi + hi*lo + lo*hi); lo*lo dropped (~2^-17 rel).
// Ping-pong register prefetch: loads for chunk c+1 issued one full phase
// before consumption (covered by convert+write+barrier+MFMA of chunk c).
// LDS per plane: 16 slabs (8 k-cols) x [64 rows][16B], slab stride 1040 B.
// Each wave owns one 32x32 output tile.
// ---------------------------------------------------------------------------
#define GR_SLAB 1040
#define GR_PLANE 16640

#define GR_LOAD(dst, cofs)                                                          \
    _Pragma("unroll") for (int i = 0; i < 8; ++i) {                                 \
        int f = t + 256 * i;                                                        \
        dst[i] = *reinterpret_cast<const float4*>(base + (size_t)(cofs) * 128 +     \
                                                  (size_t)(f >> 5) * N + (f & 31) * 4); \
    }

#define GR_CONVWRITE(srcv)                                                          \
    _Pragma("unroll") for (int i = 0; i < 8; ++i) {                                 \
        float4 x = srcv[i];                                                         \
        rs[i] += (x.x + x.y) + (x.z + x.w);                                         \
        unsigned bx = __float_as_uint(x.x), by = __float_as_uint(x.y);              \
        unsigned bz = __float_as_uint(x.z), bw = __float_as_uint(x.w);              \
        float lx = x.x - __uint_as_float(bx & 0xffff0000u);                         \
        float ly = x.y - __uint_as_float(by & 0xffff0000u);                         \
        float lz = x.z - __uint_as_float(bz & 0xffff0000u);                         \
        float lwv = x.w - __uint_as_float(bw & 0xffff0000u);                        \
        uint2 hwv = make_uint2((bx >> 16) | (by & 0xffff0000u),                     \
                               (bz >> 16) | (bw & 0xffff0000u));                    \
        uint2 lwv2 = make_uint2((__float_as_uint(lx) >> 16) | (__float_as_uint(ly) & 0xffff0000u), \
                                (__float_as_uint(lz) >> 16) | (__float_as_uint(lwv) & 0xffff0000u)); \
        int f = t + 256 * i;                                                        \
        int row = f >> 5, col4 = f & 31;                                            \
        char* dstp = smem + (col4 >> 1) * GR_SLAB + row * 16 + ((col4 & 1) << 3);   \
        *reinterpret_cast<uint2*>(dstp) = hwv;                                      \
        *reinterpret_cast<uint2*>(dstp + GR_PLANE) = lwv2;                          \
    }

#define GR_MFMA()                                                                   \
    _Pragma("unroll") for (int kc = 0; kc < 8; ++kc) {                              \
        const char* sb = smem + (2 * kc + sl) * GR_SLAB;                            \
        bf16x8 ahi = *reinterpret_cast<const bf16x8*>(sb + rA * 16);                \
        bf16x8 alo = *reinterpret_cast<const bf16x8*>(sb + GR_PLANE + rA * 16);     \
        bf16x8 bhi, blo;                                                            \
        if (diag) { bhi = ahi; blo = alo; }                                         \
        else {                                                                      \
            bhi = *reinterpret_cast<const bf16x8*>(sb + rB * 16);                   \
            blo = *reinterpret_cast<const bf16x8*>(sb + GR_PLANE + rB * 16);        \
        }                                                                           \
        acc = __builtin_amdgcn_mfma_f32_32x32x16_bf16(ahi, bhi, acc, 0, 0, 0);      \
        acc = __builtin_amdgcn_mfma_f32_32x32x16_bf16(ahi, blo, acc, 0, 0, 0);      \
        acc = __builtin_amdgcn_mfma_f32_32x32x16_bf16(alo, bhi, acc, 0, 0, 0);      \
    }

__global__ __launch_bounds__(256) void gram_kernel(const float* __restrict__ cF,
                                                   float* __restrict__ G,
                                                   float* __restrict__ Sc, int N) {
    __shared__ __align__(16) char smem[2 * GR_PLANE];
    const int b = blockIdx.x >> 7;
    const int part = blockIdx.x & 127;
    const float* base = cF + (size_t)b * 64 * N + (size_t)part * (N >> 7);
    const int t = threadIdx.x;
    const int wid = t >> 6;
    const int lane = t & 63;
    const int I = (wid >> 1) << 5;
    const int Jt = (wid & 1) << 5;
    const bool diag = (I == Jt);
    const int rA = I + (lane & 31);
    const int rB = Jt + (lane & 31);
    const int sl = lane >> 5;

    f32x16 acc = {};
    float rs[8];
#pragma unroll
    for (int i = 0; i < 8; ++i) rs[i] = 0.f;

    float4 va[8], vb[8];
    GR_LOAD(va, 0)  // chunk 0

    for (int c = 0; c < 16; c += 2) {
        if (c + 1 < 16) { GR_LOAD(vb, c + 1) }
        __syncthreads();          // prev MFMA reads done
        GR_CONVWRITE(va)          // chunk c -> LDS
        __syncthreads();          // planes ready
        GR_MFMA()
        if (c + 2 < 16) { GR_LOAD(va, c + 2) }
        __syncthreads();          // MFMA reads done
        GR_CONVWRITE(vb)          // chunk c+1 -> LDS
        __syncthreads();
        GR_MFMA()
    }

    float* Gb = G + b * 4096;
#pragma unroll
    for (int r = 0; r < 16; ++r) {
        int m = (r & 3) + 8 * (r >> 2) + 4 * (lane >> 5);
        int n = lane & 31;
        atomicAdd(&Gb[(I + m) * 64 + (Jt + n)], acc[r]);
    }
    const int baseRow = t >> 5;
#pragma unroll
    for (int i = 0; i < 8; ++i) {
        float s = rs[i];
#pragma unroll
        for (int o = 16; o > 0; o >>= 1) s += __shfl_xor(s, o);
        if ((lane & 31) == 0) atomicAdd(&Sc[b * 64 + baseRow + 8 * i], s);
    }
}

// ---------- solver: cov -> Newton-Schulz inverse sqrt -> fused transform ----------
#define SSTR 68

__device__ __forceinline__ void matmul44(float* __restrict__ D, const float* __restrict__ A,
                                         const float* __restrict__ Bm, int i0, int j0) {
    float acc[4][4];
#pragma unroll
    for (int i = 0; i < 4; ++i)
#pragma unroll
        for (int j = 0; j < 4; ++j) acc[i][j] = 0.f;
    for (int k = 0; k < 64; ++k) {
        float4 bv = *reinterpret_cast<const float4*>(&Bm[k * SSTR + j0]);
        float a0 = A[(i0 + 0) * SSTR + k];
        float a1 = A[(i0 + 1) * SSTR + k];
        float a2 = A[(i0 + 2) * SSTR + k];
        float a3 = A[(i0 + 3) * SSTR + k];
        acc[0][0] += a0 * bv.x; acc[0][1] += a0 * bv.y; acc[0][2] += a0 * bv.z; acc[0][3] += a0 * bv.w;
        acc[1][0] += a1 * bv.x; acc[1][1] += a1 * bv.y; acc[1][2] += a1 * bv.z; acc[1][3] += a1 * bv.w;
        acc[2][0] += a2 * bv.x; acc[2][1] += a2 * bv.y; acc[2][2] += a2 * bv.z; acc[2][3] += a2 * bv.w;
        acc[3][0] += a3 * bv.x; acc[3][1] += a3 * bv.y; acc[3][2] += a3 * bv.z; acc[3][3] += a3 * bv.w;
    }
#pragma unroll
    for (int i = 0; i < 4; ++i)
#pragma unroll
        for (int j = 0; j < 4; ++j) D[(i0 + i) * SSTR + j0 + j] = acc[i][j];
}

__global__ __launch_bounds__(256) void solve_kernel(const float* __restrict__ G,
                                                    const float* __restrict__ Sc,
                                                    const float* __restrict__ Ss,
                                                    const float* __restrict__ alphap,
                                                    const float* __restrict__ s_e,
                                                    const float* __restrict__ s_v,
                                                    float* __restrict__ Tg,
                                                    float* __restrict__ biasg, int N) {
    __shared__ __align__(16) float Abuf[64 * SSTR];
    __shared__ __align__(16) float Ybuf[64 * SSTR];
    __shared__ __align__(16) float Tbuf[64 * SSTR];
    __shared__ __align__(16) float Wb[64 * 20];
    __shared__ float sdv[64], mcv[64], msv[64];
    __shared__ float redv;
    const int b = blockIdx.x, t = threadIdx.x;
    const int i0 = (t >> 4) << 2, j0 = (t & 15) << 2;
    const float invN = 1.f / (float)N;
    const float invNm1 = 1.f / (float)(N - 1);
    if (t < 64) {
        mcv[t] = Sc[b * 64 + t] * invN;
        msv[t] = Ss[b * 64 + t] * invN;
        sdv[t] = sqrtf(s_e[b * 64 + t]);
    }
    __syncthreads();
#pragma unroll
    for (int i = 0; i < 4; ++i) {
        float mi = mcv[i0 + i];
#pragma unroll
        for (int j = 0; j < 4; ++j) {
            float g = G[b * 4096 + (i0 + i) * 64 + j0 + j];
            float cov = (g - mi * mcv[j0 + j] * (float)N) * invNm1 + (((i0 + i) == (j0 + j)) ? 1.f : 0.f);
            Abuf[(i0 + i) * SSTR + j0 + j] = cov;
        }
    }
    __syncthreads();
    if (t < 64) {
        float d = waveRed(Abuf[t * SSTR + t]);
        if (t == 0) redv = d * (1.f / 64.f);
    }
    __syncthreads();
    const float s = redv;
    const float inv_s = 1.f / s;
#pragma unroll
    for (int i = 0; i < 4; ++i)
#pragma unroll
        for (int j = 0; j < 4; ++j) {
            Abuf[(i0 + i) * SSTR + j0 + j] *= inv_s;
            Ybuf[(i0 + i) * SSTR + j0 + j] = ((i0 + i) == (j0 + j)) ? 1.f : 0.f;
        }
    __syncthreads();
    const int kr = t >> 2;
    const int cw = (t & 3) << 2;
    for (int it = 0; it < 3; ++it) {
        matmul44(Tbuf, Ybuf, Ybuf, i0, j0);
        __syncthreads();
        for (int lb = 0; lb < 4; ++lb) {
            const int cb = lb << 4;
            float w0 = 0.f, w1 = 0.f, w2 = 0.f, w3 = 0.f;
            for (int j = 0; j < 64; ++j) {
                float a = Abuf[kr * SSTR + j];
                float4 tv = *reinterpret_cast<const float4*>(&Tbuf[j * SSTR + cb + cw]);
                w0 += a * tv.x; w1 += a * tv.y; w2 += a * tv.z; w3 += a * tv.w;
            }
            Wb[kr * 20 + cw + 0] = ((kr == cb + cw + 0) ? 1.5f : 0.f) - 0.5f * w0;
            Wb[kr * 20 + cw + 1] = ((kr == cb + cw + 1) ? 1.5f : 0.f) - 0.5f * w1;
            Wb[kr * 20 + cw + 2] = ((kr == cb + cw + 2) ? 1.5f : 0.f) - 0.5f * w2;
            Wb[kr * 20 + cw + 3] = ((kr == cb + cw + 3) ? 1.5f : 0.f) - 0.5f * w3;
            __syncthreads();
            float y0 = 0.f, y1 = 0.f, y2 = 0.f, y3 = 0.f;
            for (int k = 0; k < 64; ++k) {
                float a = Ybuf[kr * SSTR + k];
                float4 wv = *reinterpret_cast<const float4*>(&Wb[k * 20 + cw]);
                y0 += a * wv.x; y1 += a * wv.y; y2 += a * wv.z; y3 += a * wv.w;
            }
            Tbuf[kr * SSTR + cb + cw + 0] = y0;
            Tbuf[kr * SSTR + cb + cw + 1] = y1;
            Tbuf[kr * SSTR + cb + cw + 2] = y2;
            Tbuf[kr * SSTR + cb + cw + 3] = y3;
            __syncthreads();
        }
#pragma unroll
        for (int i = 0; i < 4; ++i)
#pragma unroll
            for (int j = 0; j < 4; ++j)
                Ybuf[(i0 + i) * SSTR + j0 + j] = Tbuf[(i0 + i) * SSTR + j0 + j];
        __syncthreads();
    }
    for (int i = 0; i < 16; ++i) {
        int idx = t + 256 * i;
        Abuf[(idx >> 6) * SSTR + (idx & 63)] = s_v[b * 4096 + idx];
    }
    __syncthreads();
    {
        float acc[4][4];
#pragma unroll
        for (int i = 0; i < 4; ++i)
#pragma unroll
            for (int j = 0; j < 4; ++j) acc[i][j] = 0.f;
        for (int k = 0; k < 64; ++k) {
            float sd = sdv[k];
            float a0 = Abuf[(i0 + 0) * SSTR + k] * sd;
            float a1 = Abuf[(i0 + 1) * SSTR + k] * sd;
            float a2 = Abuf[(i0 + 2) * SSTR + k] * sd;
            float a3 = Abuf[(i0 + 3) * SSTR + k] * sd;
            float c0v = Abuf[(j0 + 0) * SSTR + k];
            float c1v = Abuf[(j0 + 1) * SSTR + k];
            float c2v = Abuf[(j0 + 2) * SSTR + k];
            float c3v = Abuf[(j0 + 3) * SSTR + k];
            acc[0][0] += a0 * c0v; acc[0][1] += a0 * c1v; acc[0][2] += a0 * c2v; acc[0][3] += a0 * c3v;
            acc[1][0] += a1 * c0v; acc[1][1] += a1 * c1v; acc[1][2] += a1 * c2v; acc[1][3] += a1 * c3v;
            acc[2][0] += a2 * c0v; acc[2][1] += a2 * c1v; acc[2][2] += a2 * c2v; acc[2][3] += a2 * c3v;
            acc[3][0] += a3 * c0v; acc[3][1] += a3 * c1v; acc[3][2] += a3 * c2v; acc[3][3] += a3 * c3v;
        }
        __syncthreads();
#pragma unroll
        for (int i = 0; i < 4; ++i)
#pragma unroll
            for (int j = 0; j < 4; ++j) Tbuf[(i0 + i) * SSTR + j0 + j] = acc[i][j];
    }
    __syncthreads();
    matmul44(Abuf, Tbuf, Ybuf, i0, j0);
    __syncthreads();
    const float alpha_v = alphap[0];
    const float fac = alpha_v / sqrtf(s);
#pragma unroll
    for (int i = 0; i < 4; ++i)
#pragma unroll
        for (int j = 0; j < 4; ++j) {
            float m = Abuf[(i0 + i) * SSTR + j0 + j] * fac;
            if ((i0 + i) == (j0 + j)) m += 1.f - alpha_v;
            Tg[b * 4096 + (i0 + i) * 64 + j0 + j] = m;
        }
    if (t < 64) {
        float acc = 0.f;
        for (int d = 0; d < 64; ++d) acc += Abuf[t * SSTR + d] * mcv[d];
        biasg[b * 64 + t] = alpha_v * msv[t] - fac * acc;
    }
}

// ---------------------------------------------------------------------------
// MFMA apply: out[c][x] = sum_k T[c][k]*cf[k][x] + bias[c], split-bf16.
// cf tile transposed into LDS as [x][k] (k contiguous, XSTR=72 halfwords =
// 144 B rows -> odd 16B-chunk stride -> conflict-free ds_read_b128).
// Staging: thread owns a 2x * 16k micro-tile: 16 coalesced dwordx2 loads +
// 8 ds_write_b128 at <=2-way conflict (vs 32 scalar writes at 16-way before).
// Tile loads issued before T-fragment prep so HBM latency hides under it.
// ---------------------------------------------------------------------------
#define APX 128
#define XSTR 72
__global__ __launch_bounds__(256) void apply_kernel(const float* __restrict__ cF,
                                                    const float* __restrict__ Tg,
                                                    const float* __restrict__ biasg,
                                                    float* __restrict__ out, int N) {
    __shared__ __align__(16) unsigned short sx[2][APX][XSTR];  // hi, lo planes
    __shared__ float bl[64];
    const int b = blockIdx.x >> 11;
    const int part = blockIdx.x & 2047;
    const float* src = cF + (size_t)b * 64 * N + (size_t)part * APX;
    float* dst = out + (size_t)b * 64 * N + (size_t)part * APX;
    const int t = threadIdx.x;
    const int lane = t & 63;
    const int wid = t >> 6;

    // --- issue tile loads first: 2x * 16k micro-tile per thread ---
    const int p2 = t & 63;            // x-pair index -> x = {2p2, 2p2+1}
    const int koct = (t >> 6) << 4;   // 16 consecutive k
    float2 vv[16];
#pragma unroll
    for (int j = 0; j < 16; ++j)
        vv[j] = *reinterpret_cast<const float2*>(src + (size_t)(koct + j) * N + 2 * p2);

    if (t < 64) bl[t] = biasg[b * 64 + t];

    // --- T fragments (A operand), split bf16 hi/lo, from global (L2-hot) ---
    const int I = (wid & 1) << 5;        // channel block
    const int xb0 = (wid >> 1) << 6;     // pixel block (0 or 64)
    const int kb = (lane >> 5) << 3;     // k sub-slab within 16-k slab
    bf16x8 th[4], tl[4];
    {
        const float* Trow = Tg + b * 4096 + (size_t)(I + (lane & 31)) * 64;
#pragma unroll
        for (int ks = 0; ks < 4; ++ks) {
            float4 u0 = *reinterpret_cast<const float4*>(Trow + ks * 16 + kb);
            float4 u1 = *reinterpret_cast<const float4*>(Trow + ks * 16 + kb + 4);
            float v[8] = {u0.x, u0.y, u0.z, u0.w, u1.x, u1.y, u1.z, u1.w};
#pragma unroll
            for (int j = 0; j < 8; ++j) {
                unsigned u = __float_as_uint(v[j]);
                th[ks][j] = (short)(u >> 16);
                float r = v[j] - __uint_as_float(u & 0xffff0000u);
                tl[ks][j] = (short)(__float_as_uint(r) >> 16);
            }
        }
    }

    // --- convert micro-tile -> split-bf16 planes, b128 writes ---
#pragma unroll
    for (int xx = 0; xx < 2; ++xx) {
#pragma unroll
        for (int ch = 0; ch < 2; ++ch) {  // two 8-k chunks
            unsigned h0, h1, h2, h3, l0, l1, l2, l3;
#define CONV_PAIR(jp, HO, LO)                                                     \
            {                                                                     \
                float a = xx ? vv[ch * 8 + 2 * jp].y : vv[ch * 8 + 2 * jp].x;     \
                float bq = xx ? vv[ch * 8 + 2 * jp + 1].y : vv[ch * 8 + 2 * jp + 1].x; \
                unsigned ua = __float_as_uint(a), ub = __float_as_uint(bq);       \
                float ra = a - __uint_as_float(ua & 0xffff0000u);                 \
                float rb = bq - __uint_as_float(ub & 0xffff0000u);                \
                HO = (ua >> 16) | (ub & 0xffff0000u);                             \
                LO = (__float_as_uint(ra) >> 16) | (__float_as_uint(rb) & 0xffff0000u); \
            }
            CONV_PAIR(0, h0, l0)
            CONV_PAIR(1, h1, l1)
            CONV_PAIR(2, h2, l2)
            CONV_PAIR(3, h3, l3)
#undef CONV_PAIR
            uint4 H; H.x = h0; H.y = h1; H.z = h2; H.w = h3;
            uint4 L; L.x = l0; L.y = l1; L.z = l2; L.w = l3;
            *reinterpret_cast<uint4*>(&sx[0][2 * p2 + xx][koct + ch * 8]) = H;
            *reinterpret_cast<uint4*>(&sx[1][2 * p2 + xx][koct + ch * 8]) = L;
        }
    }
    __syncthreads();

    // --- MFMA: acc = T_hi*x_hi + T_hi*x_lo + T_lo*x_hi ---
    f32x16 acc0 = {}, acc1 = {};
    const int xA = xb0 + (lane & 31);
#pragma unroll
    for (int ks = 0; ks < 4; ++ks) {
        const int ko = ks * 16 + kb;
        bf16x8 bh0 = *reinterpret_cast<const bf16x8*>(&sx[0][xA][ko]);
        bf16x8 bL0 = *reinterpret_cast<const bf16x8*>(&sx[1][xA][ko]);
        bf16x8 bh1 = *reinterpret_cast<const bf16x8*>(&sx[0][xA + 32][ko]);
        bf16x8 bL1 = *reinterpret_cast<const bf16x8*>(&sx[1][xA + 32][ko]);
        acc0 = __builtin_amdgcn_mfma_f32_32x32x16_bf16(th[ks], bh0, acc0, 0, 0, 0);
        acc0 = __builtin_amdgcn_mfma_f32_32x32x16_bf16(th[ks], bL0, acc0, 0, 0, 0);
        acc0 = __builtin_amdgcn_mfma_f32_32x32x16_bf16(tl[ks], bh0, acc0, 0, 0, 0);
        acc1 = __builtin_amdgcn_mfma_f32_32x32x16_bf16(th[ks], bh1, acc1, 0, 0, 0);
        acc1 = __builtin_amdgcn_mfma_f32_32x32x16_bf16(th[ks], bL1, acc1, 0, 0, 0);
        acc1 = __builtin_amdgcn_mfma_f32_32x32x16_bf16(tl[ks], bh1, acc1, 0, 0, 0);
    }

    // --- store + bias: C/D layout col=lane&31, row=(r&3)+8*(r>>2)+4*(lane>>5) ---
#pragma unroll
    for (int r = 0; r < 16; ++r) {
        int m = (r & 3) + 8 * (r >> 2) + 4 * (lane >> 5);
        float bb = bl[I + m];
        float* dr = dst + (size_t)(I + m) * N;
        dr[xA] = acc0[r] + bb;
        dr[xA + 32] = acc1[r] + bb;
    }
}

extern "C" void kernel_launch(void* const* d_in, const int* in_sizes, int n_in,
                              void* d_out, int out_size, void* d_ws, size_t ws_size,
                              hipStream_t stream) {
    const float* cF = (const float*)d_in[0];
    const float* sF = (const float*)d_in[1];
    const float* alpha = (const float*)d_in[2];
    const float* s_e = (const float*)d_in[3];
    const float* s_v = (const float*)d_in[4];
    float* out = (float*)d_out;
    float* ws = (float*)d_ws;
    const int B = 4, C = 64;
    const int N = in_sizes[0] / (B * C);  // 262144
    float* G = ws + WS_G;
    float* Sc = ws + WS_SC;
    float* Ss = ws + WS_SS;
    float* T = ws + WS_T;
    float* bias = ws + WS_BIAS;
    hipLaunchKernelGGL(zero_kernel, dim3(66), dim3(256), 0, stream, ws, WS_ZERO_COUNT);
    hipLaunchKernelGGL(sum_kernel, dim3(B * C * 8), dim3(256), 0, stream, sF, Ss, N);
    hipLaunchKernelGGL(gram_kernel, dim3(B * 128), dim3(256), 0, stream, cF, G, Sc, N);
    hipLaunchKernelGGL(solve_kernel, dim3(B), dim3(256), 0, stream, G, Sc, Ss, alpha, s_e, s_v, T, bias, N);
    hipLaunchKernelGGL(apply_kernel, dim3(B * 2048), dim3(256), 0, stream, cF, T, bias, out, N);
}